// Round 4
// baseline (33677.460 us; speedup 1.0000x reference)
//
#include <hip/hip_runtime.h>

// Dilated 3-layer LSTM, T=512, B=128, D=H=256, rates {1,2,4}.
//
// v5: v4 skeleton + lean sync protocol.
//   - gate-per-wave: wave wv owns hid subtile wv*16..+16 with ALL 4 gates ->
//     i,f,g,o in-lane, no scr LDS exchange, no barrier C.
//   - sibling h(t-1) quarters read straight into A-fragments from the ring
//     (no LDS staging barrier); own quarter via 4KB swizzled LDS dbuf.
//   - ring/out/h16 stores are NONTEMPORAL -> L2 stays clean -> the agent
//     release's buffer_wbl2 is ~free (v4 drained all dirty outputs per step).
//   - release = monotonic __hip_atomic_store(t+1) (single writer, padded
//     flag), poll = relaxed spin by 3 lane-0 pollers + one
//     fence(acquire,"agent") after the barrier (v4 did a 256-thread acquire).
//   - out/h16 stores after the release (off the critical chain).
// Falls back to the original verified ring-sync kernel if ws_size is small.

typedef _Float16 half8   __attribute__((ext_vector_type(8)));
typedef _Float16 half4_t __attribute__((ext_vector_type(4)));
typedef float    floatx4 __attribute__((ext_vector_type(4)));

__device__ __forceinline__ float sigmf(float x) {
    return 1.0f / (1.0f + __expf(-x));
}
__device__ __forceinline__ float tanhfast(float x) {
    float e = __expf(-2.0f * fabsf(x));
    float r = (1.0f - e) / (1.0f + e);
    return copysignf(r, x);
}

#define MFMA16(A, B, C) __builtin_amdgcn_mfma_f32_16x16x32_f16((A), (B), (C), 0, 0, 0)

#define RING_STRIDE (512 * 256)        // fp16 elements per ring slot (max N=512)
#define BR_SLOTS    2
#define BR_RING_BYTES (BR_SLOTS * RING_STRIDE * 2)
#define CNT_PER_LAYER 8192             // 128 blocks x 64-int padding
#define CNT_INTS      24576

// ---------------------------------------------------------------------------
// prep: pack weights into B-fragment layout + combined bias
// frag(l,w8,ct8,ks): lane ln holds W[col][k..k+8),
// col=(ct8>>1)*256 + w8*32 + (ct8&1)*16 + (ln&15), k = ks*32 + (ln>>4)*8.
// Layout: pack[l][(w8*8+ct8)*8+ks][ln][8] halves.  (gate = ct8>>1, i,f,g,o)
// ---------------------------------------------------------------------------
__global__ void prep_kernel(
    const float* __restrict__ Wih, const float* __restrict__ Whh,
    const float* __restrict__ bih, const float* __restrict__ bhh,
    _Float16* __restrict__ wihp, _Float16* __restrict__ whhp,
    float* __restrict__ biasc)
{
    int id = blockIdx.x * 256 + threadIdx.x;
    if (id < 196608) {
        int u = id;
        const float* W = Whh; _Float16* P = whhp;
        if (u >= 98304) { W = Wih; P = wihp; u -= 98304; }
        int ln = u & 63; u >>= 6;
        int ks = u & 7;  u >>= 3;
        int ct = u & 7;  u >>= 3;
        int w  = u & 7;  u >>= 3;
        int l  = u;                                  // 0..2
        int col = (ct >> 1) * 256 + w * 32 + (ct & 1) * 16 + (ln & 15);
        int k0  = ks * 32 + (ln >> 4) * 8;
        const float* src = W + ((size_t)l * 1024 + col) * 256 + k0;
        half8 hv;
#pragma unroll
        for (int j = 0; j < 8; ++j) hv[j] = (_Float16)src[j];
        *(half8*)(P + (size_t)l * 262144 +
                  (size_t)(((w * 8 + ct) * 8 + ks) * 64 + ln) * 8) = hv;
    } else if (id < 199680) {
        int v = id - 196608;                         // 3*1024 combined biases
        biasc[v] = bih[v] + bhh[v];
    }
}

// ---------------------------------------------------------------------------
// gx GEMM: block = 64 packed rows x 256 gate cols (one w8-pair), 8 waves.
// Output fp16 C-fragment order: gx[((t*NB8+bg)*8+w8)*4+cp][lane][8],
// hv[rg]=parity0 rows q*4+rg (hid w8*32+r15), hv[4+rg]=parity1 (+16).
// ---------------------------------------------------------------------------
template<int F16IN>
__global__ __launch_bounds__(512, 1) void gx_kernel(
    const float* __restrict__ in32,
    const _Float16* __restrict__ in16,
    const _Float16* __restrict__ wpack,   // layer slice
    const float* __restrict__ biasc,      // layer slice (1024)
    _Float16* __restrict__ gx,
    int rate, int RB, int NB8)
{
    __shared__ _Float16 Ab[64][264];
    const int tid = threadIdx.x, lane = tid & 63, w = tid >> 6;
    const int cb  = blockIdx.x & 3;
    const int nbi = (blockIdx.x >> 2) % RB;
    const int t   = (blockIdx.x >> 2) / RB;
    const int r15 = lane & 15, q = lane >> 4;
    const int w8  = 2 * cb + (w & 1);
    const int cp  = w >> 1;

#pragma unroll
    for (int i = 0; i < 4; ++i) {
        int id = tid + 512 * i;
        int row = id >> 5, c16 = id & 31;
        int n = nbi * 64 + row;
        size_t base = ((size_t)(t * rate + (n >> 7)) * 128 + (n & 127)) * 256 + c16 * 8;
        if (F16IN) {
            *(uint4*)&Ab[row][c16 * 8] = *(const uint4*)(in16 + base);
        } else {
            floatx4 v0 = *(const floatx4*)(in32 + base);
            floatx4 v1 = *(const floatx4*)(in32 + base + 4);
            half8 hv;
            hv[0] = (_Float16)v0[0]; hv[1] = (_Float16)v0[1];
            hv[2] = (_Float16)v0[2]; hv[3] = (_Float16)v0[3];
            hv[4] = (_Float16)v1[0]; hv[5] = (_Float16)v1[1];
            hv[6] = (_Float16)v1[2]; hv[7] = (_Float16)v1[3];
            *(half8*)&Ab[row][c16 * 8] = hv;
        }
    }
    __syncthreads();

    floatx4 zero4 = {0.f, 0.f, 0.f, 0.f};
    floatx4 acc[4][2];
#pragma unroll
    for (int rt = 0; rt < 4; ++rt) { acc[rt][0] = zero4; acc[rt][1] = zero4; }

    const _Float16* wb = wpack + (size_t)((w8 * 8 + 2 * cp) * 8) * 512 +
                         (size_t)lane * 8;
#pragma unroll
    for (int ks = 0; ks < 8; ++ks) {
        half8 bf0 = *(const half8*)(wb + (size_t)(0 * 8 + ks) * 512);
        half8 bf1 = *(const half8*)(wb + (size_t)(1 * 8 + ks) * 512);
        half8 a0 = *(const half8*)&Ab[ 0 + r15][ks * 32 + q * 8];
        half8 a1 = *(const half8*)&Ab[16 + r15][ks * 32 + q * 8];
        half8 a2 = *(const half8*)&Ab[32 + r15][ks * 32 + q * 8];
        half8 a3 = *(const half8*)&Ab[48 + r15][ks * 32 + q * 8];
        acc[0][0] = MFMA16(a0, bf0, acc[0][0]); acc[0][1] = MFMA16(a0, bf1, acc[0][1]);
        acc[1][0] = MFMA16(a1, bf0, acc[1][0]); acc[1][1] = MFMA16(a1, bf1, acc[1][1]);
        acc[2][0] = MFMA16(a2, bf0, acc[2][0]); acc[2][1] = MFMA16(a2, bf1, acc[2][1]);
        acc[3][0] = MFMA16(a3, bf0, acc[3][0]); acc[3][1] = MFMA16(a3, bf1, acc[3][1]);
    }

    const float be0 = biasc[cp * 256 + w8 * 32 + r15];
    const float be1 = biasc[cp * 256 + w8 * 32 + 16 + r15];
#pragma unroll
    for (int rt = 0; rt < 4; ++rt) {
        int bg = nbi * 4 + rt;
        half8 hv;
#pragma unroll
        for (int rg = 0; rg < 4; ++rg) {
            hv[rg]     = (_Float16)(acc[rt][0][rg] + be0);
            hv[4 + rg] = (_Float16)(acc[rt][1][rg] + be1);
        }
        *(half8*)(gx + ((((size_t)t * NB8 + bg) * 8 + w8) * 4 + cp) * 512 +
                  (size_t)lane * 8) = hv;
    }
}

// ---------------------------------------------------------------------------
// scan5: grid = 4*NB8 blocks of 256 threads (4 waves).
// Block b: bg = b%NB8 (16 batch rows), hb = b/NB8 (hidden quarter).
// Wave wv owns hid subtile hb*64 + wv*16..+16, ALL 4 gates in-lane.
// ---------------------------------------------------------------------------
__global__ __launch_bounds__(256, 1) void scan5_kernel(
    const _Float16* __restrict__ gx,
    const _Float16* __restrict__ wpack,   // layer slice of whhp
    float* __restrict__ out,
    _Float16* __restrict__ h16,
    _Float16* __restrict__ ring,
    int* __restrict__ flg,                // layer slice, 64-int padded per block
    int rate, int td, int NB8)
{
    __shared__ _Float16 OwnH[2][2048];    // [dbuf][16 rows x 64 hid] XOR-swizzled

    const int tid  = threadIdx.x;
    const int lane = tid & 63;
    const int wv   = tid >> 6;
    const int r15  = lane & 15;
    const int q    = lane >> 4;
    const int bg   = blockIdx.x % NB8;
    const int hb   = blockIdx.x / NB8;    // hidden quarter 0..3
    const int n0   = bg * 16;
    const int myb  = blockIdx.x;
    const int w8   = 2 * hb + (wv >> 1);
    const int par  = wv & 1;
    const int hidg = hb * 64 + wv * 16 + r15;

    // ---- Whh: all 4 gates for this wave's 16-hid subtile (128 VGPR), pinned ----
    half8 wf[4][8];
#pragma unroll
    for (int g = 0; g < 4; ++g) {
        const int ct8 = 2 * g + par;
#pragma unroll
        for (int ks = 0; ks < 8; ++ks) {
            wf[g][ks] = *(const half8*)(wpack +
                (size_t)(((w8 * 8 + ct8) * 8 + ks) * 64 + lane) * 8);
            asm volatile("" : "+v"(wf[g][ks]));   // non-rematerializable
        }
    }

    // zero OwnH[0] (h(-1) = 0): 2048 halfs / 256 threads = 8 each
    {
        half8 z;
#pragma unroll
        for (int j = 0; j < 8; ++j) z[j] = (_Float16)0.0f;
        *(half8*)&OwnH[0][tid * 8] = z;
    }

    // gx(0) -> registers (4 gate frags per wave; halves selected by par)
    const size_t gxstep = (size_t)NB8 * 16384;
    const _Float16* gxb = gx + ((size_t)bg * 8 + w8) * 4 * 512 + (size_t)lane * 8;
    half8 gxc[4];
#pragma unroll
    for (int g = 0; g < 4; ++g) gxc[g] = *(const half8*)(gxb + g * 512);

    float cst[4] = {0.f, 0.f, 0.f, 0.f};

    for (int t = 0; t < td; ++t) {
        const int rd = t & 1, wr = rd ^ 1;

        half8 af[8];
        if (t > 0) {
            if (lane == 0 && wv < 3) {            // 3 parallel pollers
                const int s = wv + (wv >= hb ? 1 : 0);
                while (__hip_atomic_load(&flg[(s * NB8 + bg) * 64],
                                         __ATOMIC_RELAXED,
                                         __HIP_MEMORY_SCOPE_AGENT) < t) { }
            }
            __syncthreads();                                   // A
            __builtin_amdgcn_fence(__ATOMIC_ACQUIRE, "agent"); // one fence, all
            // sibling h quarters -> A-fragments directly (MALL/L2 read)
            const _Float16* rs = ring + (size_t)((t - 1) & 1) * RING_STRIDE +
                                 (size_t)(n0 + r15) * 256 + q * 8;
#pragma unroll
            for (int si = 0; si < 3; ++si) {
                const int s = si + (si >= hb ? 1 : 0);
                af[2 * s]     = *(const half8*)(rs + s * 64);
                af[2 * s + 1] = *(const half8*)(rs + s * 64 + 32);
            }
        } else {
            __syncthreads();
            half8 z;
#pragma unroll
            for (int j = 0; j < 8; ++j) z[j] = (_Float16)0.0f;
#pragma unroll
            for (int si = 0; si < 3; ++si) {
                const int s = si + (si >= hb ? 1 : 0);
                af[2 * s] = z; af[2 * s + 1] = z;
            }
        }

        // own quarter from swizzled LDS (written by cell at t-1)
#pragma unroll
        for (int kk = 0; kk < 2; ++kk) {
            const int bo = rd * 4096 + r15 * 128 +
                           ((kk * 64 + q * 16) ^ ((r15 & 7) << 4));
            af[2 * hb + kk] = *(const half8*)((const char*)&OwnH[0][0] + bo);
        }

        floatx4 acc[4];
#pragma unroll
        for (int g = 0; g < 4; ++g)
#pragma unroll
            for (int rg = 0; rg < 4; ++rg)
                acc[g][rg] = (float)gxc[g][par * 4 + rg];

#pragma unroll
        for (int ks = 0; ks < 8; ++ks) {
            acc[0] = MFMA16(af[ks], wf[0][ks], acc[0]);
            acc[1] = MFMA16(af[ks], wf[1][ks], acc[1]);
            acc[2] = MFMA16(af[ks], wf[2][ks], acc[2]);
            acc[3] = MFMA16(af[ks], wf[3][ks], acc[3]);
        }

        // cell: all 4 gates in-lane; rows q*4+rg, hidden hidg
        float hv[4];
        _Float16* rw_ = ring + (size_t)(t & 1) * RING_STRIDE;
#pragma unroll
        for (int rg = 0; rg < 4; ++rg) {
            float c = sigmf(acc[1][rg]) * cst[rg] +
                      sigmf(acc[0][rg]) * tanhfast(acc[2][rg]);
            cst[rg] = c;
            float h = sigmf(acc[3][rg]) * tanhfast(c);
            hv[rg] = h;
            const int row = q * 4 + rg;
            const int bo = wr * 4096 + row * 128 +
                           (((wv * 16 + r15) * 2) ^ ((row & 7) << 4));
            *(_Float16*)((char*)&OwnH[0][0] + bo) = (_Float16)h;
            __builtin_nontemporal_store((_Float16)h,
                rw_ + (size_t)(n0 + row) * 256 + hidg);
        }

        __syncthreads();   // B: ring nt stores + OwnH writes drained
        if (tid == 0)
            __hip_atomic_store(&flg[myb * 64], t + 1, __ATOMIC_RELEASE,
                               __HIP_MEMORY_SCOPE_AGENT);

        // outputs (off the critical chain, nontemporal -> L2 stays clean)
#pragma unroll
        for (int rg = 0; rg < 4; ++rg) {
            const int n = n0 + q * 4 + rg;
            const int tau = t * rate + (n >> 7);
            const size_t off = ((size_t)tau * 128 + (n & 127)) * 256 + hidg;
            __builtin_nontemporal_store(hv[rg], out + off);
            __builtin_nontemporal_store((_Float16)hv[rg], h16 + off);
        }

        // prefetch gx(t+1) -> registers (drained by next fence)
        {
            const int tn = (t + 1 < td) ? (t + 1) : t;
            const _Float16* gp = gxb + (size_t)tn * gxstep;
#pragma unroll
            for (int g = 0; g < 4; ++g)
                gxc[g] = *(const half8*)(gp + g * 512);
        }
    }
}

// ===========================================================================
// FALLBACK: original verified kernel (ring + 16-way agent-scope sync), used
// only if ws_size cannot hold the gx buffer.
// ===========================================================================
#define GH 16
#define NB 32
#define FB_RING_SLOTS 4
#define FB_RING_BYTES (FB_RING_SLOTS * RING_STRIDE * 2)
#define FB_CNT_INTS 6144

__global__ __launch_bounds__(256) void lstm_layer_kernel(
    const float* __restrict__ in,
    const float* __restrict__ Wih,
    const float* __restrict__ Whh,
    const float* __restrict__ bih,
    const float* __restrict__ bhh,
    float* __restrict__ out,
    _Float16* __restrict__ ring,
    int* __restrict__ cnt,
    int rate, int td, int G_b)
{
    __shared__ _Float16 Abuf[NB][520];
    __shared__ float scr[NB][68];

    const int tid  = threadIdx.x;
    const int lane = tid & 63;
    const int wv   = tid >> 6;
    const int g_b  = blockIdx.x % G_b;
    const int g_h  = blockIdx.x / G_b;
    const int hid0 = g_h * 16;
    const int n0   = g_b * NB;

    half8 bfrag[16];
    {
        const int col  = lane & 15;
        const int qq   = lane >> 4;
        const int grow = wv * 256 + hid0 + col;
        const float* wih_row = Wih + (size_t)grow * 256;
        const float* whh_row = Whh + (size_t)grow * 256;
#pragma unroll
        for (int ks = 0; ks < 16; ++ks) {
            const int k0 = ks * 32 + qq * 8;
            const float* src = (k0 < 256) ? (wih_row + k0) : (whh_row + (k0 - 256));
            floatx4 w0 = *(const floatx4*)(src);
            floatx4 w1 = *(const floatx4*)(src + 4);
            half8 hb;
            hb[0] = (_Float16)w0[0]; hb[1] = (_Float16)w0[1];
            hb[2] = (_Float16)w0[2]; hb[3] = (_Float16)w0[3];
            hb[4] = (_Float16)w1[0]; hb[5] = (_Float16)w1[1];
            hb[6] = (_Float16)w1[2]; hb[7] = (_Float16)w1[3];
            bfrag[ks] = hb;
        }
    }

    const int erow = tid >> 4;
    const int ehid = tid & 15;
    const float bi = bih[0 * 256 + hid0 + ehid] + bhh[0 * 256 + hid0 + ehid];
    const float bf = bih[1 * 256 + hid0 + ehid] + bhh[1 * 256 + hid0 + ehid];
    const float bg = bih[2 * 256 + hid0 + ehid] + bhh[2 * 256 + hid0 + ehid];
    const float bo = bih[3 * 256 + hid0 + ehid] + bhh[3 * 256 + hid0 + ehid];
    float c0 = 0.0f, c1 = 0.0f;

    floatx4 xp[8];
#pragma unroll
    for (int i = 0; i < 8; ++i) {
        int id  = tid + 256 * i;
        int row = id >> 6;
        int m   = n0 + row;
        const float* p = in + ((size_t)(0 * rate + (m >> 7)) * 128 + (m & 127)) * 256
                         + (size_t)(id & 63) * 4;
        xp[i] = *(const floatx4*)p;
    }

    for (int t = 0; t < td; ++t) {
#pragma unroll
        for (int i = 0; i < 8; ++i) {
            int id  = tid + 256 * i;
            int row = id >> 6;
            int c4  = (id & 63) * 4;
            half4_t hx;
            hx[0] = (_Float16)xp[i][0]; hx[1] = (_Float16)xp[i][1];
            hx[2] = (_Float16)xp[i][2]; hx[3] = (_Float16)xp[i][3];
            *(half4_t*)&Abuf[row][c4] = hx;
        }
        if (t + 1 < td) {
#pragma unroll
            for (int i = 0; i < 8; ++i) {
                int id  = tid + 256 * i;
                int row = id >> 6;
                int m   = n0 + row;
                const float* p = in + ((size_t)((t + 1) * rate + (m >> 7)) * 128 + (m & 127)) * 256
                                 + (size_t)(id & 63) * 4;
                xp[i] = *(const floatx4*)p;
            }
        }
        if (t > 0) {
            const int ci = g_b * td + (t - 1);
            if (tid == 0) {
                while (__hip_atomic_load(&cnt[ci], __ATOMIC_RELAXED,
                                         __HIP_MEMORY_SCOPE_AGENT) < GH) {
                    __builtin_amdgcn_s_sleep(1);
                }
            }
            __syncthreads();
            (void)__hip_atomic_load(&cnt[ci], __ATOMIC_ACQUIRE, __HIP_MEMORY_SCOPE_AGENT);
            const _Float16* rs = ring + (size_t)((t - 1) & 3) * RING_STRIDE;
#pragma unroll
            for (int i = 0; i < 4; ++i) {
                int id  = tid + 256 * i;
                int row = id >> 5;
                int kc  = id & 31;
                int m   = n0 + row;
                uint4 v = *(const uint4*)(rs + (size_t)m * 256 + kc * 8);
                *(uint4*)&Abuf[row][256 + kc * 8] = v;
            }
        } else {
#pragma unroll
            for (int i = 0; i < 4; ++i) {
                int id  = tid + 256 * i;
                int row = id >> 5;
                int kc  = id & 31;
                uint4 z = {0u, 0u, 0u, 0u};
                *(uint4*)&Abuf[row][256 + kc * 8] = z;
            }
        }
        __syncthreads();

        floatx4 acc0 = {0.f, 0.f, 0.f, 0.f};
        floatx4 acc1 = {0.f, 0.f, 0.f, 0.f};
        {
            const int r  = lane & 15;
            const int qq = lane >> 4;
#pragma unroll
            for (int ks = 0; ks < 16; ++ks) {
                half8 a0 = *(const half8*)&Abuf[r][ks * 32 + qq * 8];
                half8 a1 = *(const half8*)&Abuf[16 + r][ks * 32 + qq * 8];
                acc0 = MFMA16(a0, bfrag[ks], acc0);
                acc1 = MFMA16(a1, bfrag[ks], acc1);
            }
        }
        {
            const int r  = lane & 15;
            const int qq = lane >> 4;
#pragma unroll
            for (int reg = 0; reg < 4; ++reg) {
                scr[qq * 4 + reg][wv * 16 + r]      = acc0[reg];
                scr[16 + qq * 4 + reg][wv * 16 + r] = acc1[reg];
            }
        }
        __syncthreads();

        {
            float gi0 = scr[erow][ehid]           + bi;
            float gf0 = scr[erow][16 + ehid]      + bf;
            float gg0 = scr[erow][32 + ehid]      + bg;
            float go0 = scr[erow][48 + ehid]      + bo;
            float gi1 = scr[16 + erow][ehid]      + bi;
            float gf1 = scr[16 + erow][16 + ehid] + bf;
            float gg1 = scr[16 + erow][32 + ehid] + bg;
            float go1 = scr[16 + erow][48 + ehid] + bo;

            c0 = sigmf(gf0) * c0 + sigmf(gi0) * tanhfast(gg0);
            c1 = sigmf(gf1) * c1 + sigmf(gi1) * tanhfast(gg1);
            float h0v = sigmf(go0) * tanhfast(c0);
            float h1v = sigmf(go1) * tanhfast(c1);

            int m0 = n0 + erow, m1 = m0 + 16;
            int tau0 = t * rate + (m0 >> 7);
            int tau1 = t * rate + (m1 >> 7);
            out[((size_t)tau0 * 128 + (m0 & 127)) * 256 + hid0 + ehid] = h0v;
            out[((size_t)tau1 * 128 + (m1 & 127)) * 256 + hid0 + ehid] = h1v;

            _Float16* rw_ = ring + (size_t)(t & 3) * RING_STRIDE;
            rw_[(size_t)m0 * 256 + hid0 + ehid] = (_Float16)h0v;
            rw_[(size_t)m1 * 256 + hid0 + ehid] = (_Float16)h1v;
        }

        __syncthreads();
        if (tid == 0) {
            __hip_atomic_fetch_add(&cnt[g_b * td + t], 1, __ATOMIC_RELEASE,
                                   __HIP_MEMORY_SCOPE_AGENT);
        }
    }
}

// ===========================================================================
extern "C" void kernel_launch(void* const* d_in, const int* in_sizes, int n_in,
                              void* d_out, int out_size, void* d_ws, size_t ws_size,
                              hipStream_t stream) {
    const float* x   = (const float*)d_in[0];
    const float* Wih = (const float*)d_in[1];   // (3, 1024, 256)
    const float* Whh = (const float*)d_in[2];   // (3, 1024, 256)
    const float* bih = (const float*)d_in[3];   // (3, 1024)
    const float* bhh = (const float*)d_in[4];   // (3, 1024)
    float* out = (float*)d_out;                 // (3, 512, 128, 256)

    const size_t GX_BYTES   = 134217728ull;     // 512*128*1024 fp16
    const size_t H16_BYTES  = 33554432ull;      // 512*128*256 fp16
    const size_t WP_BYTES   = 1572864ull;       // per packed array (3 layers)
    const size_t BIAS_BYTES = 12288ull;
    const size_t NEED = GX_BYTES + H16_BYTES + 2 * WP_BYTES + BIAS_BYTES +
                        BR_RING_BYTES + (size_t)CNT_INTS * 4;

    if (ws_size >= NEED) {
        char* p = (char*)d_ws;
        _Float16* gxb   = (_Float16*)p;                p += GX_BYTES;
        _Float16* h16   = (_Float16*)p;                p += H16_BYTES;
        _Float16* whhp  = (_Float16*)p;                p += WP_BYTES;
        _Float16* wihp  = (_Float16*)p;                p += WP_BYTES;
        float*    biasc = (float*)p;                   p += BIAS_BYTES;
        _Float16* ring  = (_Float16*)p;                p += BR_RING_BYTES;
        int*      cnt   = (int*)p;

        hipMemsetAsync(cnt, 0, (size_t)CNT_INTS * 4, stream);
        prep_kernel<<<dim3(780), dim3(256), 0, stream>>>(
            Wih, Whh, bih, bhh, wihp, whhp, biasc);

        const int rates[3] = {1, 2, 4};
        for (int l = 0; l < 3; ++l) {
            const int rate = rates[l];
            const int td   = 512 / rate;
            const int NB8  = rate * 8;          // 16-row batch groups
            const int RB   = rate * 2;          // 64-row blocks per t
            float* out_l = out + (size_t)l * 512 * 128 * 256;
            if (l == 0)
                gx_kernel<0><<<dim3(td * RB * 4), dim3(512), 0, stream>>>(
                    x, nullptr, wihp + (size_t)l * 262144, biasc + l * 1024,
                    gxb, rate, RB, NB8);
            else
                gx_kernel<1><<<dim3(td * RB * 4), dim3(512), 0, stream>>>(
                    nullptr, h16, wihp + (size_t)l * 262144, biasc + l * 1024,
                    gxb, rate, RB, NB8);
            scan5_kernel<<<dim3(4 * NB8), dim3(256), 0, stream>>>(
                gxb, whhp + (size_t)l * 262144, out_l, h16, ring,
                cnt + l * CNT_PER_LAYER, rate, td, NB8);
        }
        return;
    }

    // -------- fallback: original verified path --------
    _Float16* ring = (_Float16*)d_ws;
    int* cnt = (int*)((char*)d_ws + FB_RING_BYTES);
    hipMemsetAsync(cnt, 0, FB_CNT_INTS * sizeof(int), stream);

    const int rates[3]  = {1, 2, 4};
    const int cntOff[3] = {0, 2048, 4096};
    const float* in_ptr = x;
    for (int l = 0; l < 3; ++l) {
        const int rate = rates[l];
        const int td   = 512 / rate;
        const int N    = rate * 128;
        const int G_b  = N / NB;
        lstm_layer_kernel<<<dim3(G_b * GH), dim3(256), 0, stream>>>(
            in_ptr,
            Wih + (size_t)l * 1024 * 256,
            Whh + (size_t)l * 1024 * 256,
            bih + (size_t)l * 1024,
            bhh + (size_t)l * 1024,
            out + (size_t)l * 512 * 128 * 256,
            ring, cnt + cntOff[l],
            rate, td, G_b);
        in_ptr = out + (size_t)l * 512 * 128 * 256;
    }
}